// Round 6
// baseline (636.333 us; speedup 1.0000x reference)
//
#include <hip/hip_runtime.h>

#define N_NODES 500000
#define N_EDGES 5000000
#define D 16
#define BSH 9
#define BSZ 512                          // nodes per dst bucket
#define NB ((N_NODES + BSZ - 1) / BSZ)   // 977 dst buckets
#define TSH 16                           // src tile = 65536 nodes = 4MB of x
#define NT 8                             // ceil(500000 / 65536)
#define NBK (NB * NT)                    // 7816 (dst-bucket, src-tile) bins
#define CH 16384                         // edges per place-block chunk
#define PBLK ((N_EDGES + CH - 1) / CH)   // 306 blocks

// ---- K1: (dst-bucket, src-tile) histogram (LDS-privatized) ----------------
__global__ __launch_bounds__(256) void hist_k(const int* __restrict__ esrc,
                                              const int* __restrict__ edst,
                                              int* __restrict__ bhist) {
    __shared__ int h[NBK];
    for (int i = threadIdx.x; i < NBK; i += 256) h[i] = 0;
    __syncthreads();
    int stride = gridDim.x * blockDim.x;
    for (int e = blockIdx.x * blockDim.x + threadIdx.x; e < N_EDGES; e += stride) {
        int key = ((edst[e] >> BSH) << 3) | (esrc[e] >> TSH);
        atomicAdd(&h[key], 1);
    }
    __syncthreads();
    for (int i = threadIdx.x; i < NBK; i += 256)
        if (h[i]) atomicAdd(&bhist[i], h[i]);
}

// ---- K2: exclusive scan of 7816 bin counts (1 block, 8 per thread) --------
__global__ void scan_k(const int* __restrict__ bhist, int* __restrict__ boffk,
                       int* __restrict__ cursor) {
    __shared__ int s[1024];
    int t = threadIdx.x;
    int v[8]; int sum = 0;
#pragma unroll
    for (int j = 0; j < 8; ++j) {
        int i = 8 * t + j;
        v[j] = (i < NBK) ? bhist[i] : 0;
        sum += v[j];
    }
    s[t] = sum; __syncthreads();
    for (int off = 1; off < 1024; off <<= 1) {
        int u = (t >= off) ? s[t - off] : 0;
        __syncthreads(); s[t] += u; __syncthreads();
    }
    int base = s[t] - sum;
#pragma unroll
    for (int j = 0; j < 8; ++j) {
        int i = 8 * t + j;
        if (i < NBK) { boffk[i] = base; cursor[i] = base; }
        base += v[j];
    }
    if (t == 1023) boffk[NBK] = N_EDGES;
}

// ---- K3: bulk-reserve counting-sort placement (key-major) -----------------
__global__ __launch_bounds__(256) void place_k(const int* __restrict__ esrc,
                                               const int* __restrict__ edst,
                                               int* __restrict__ cursor,
                                               unsigned* __restrict__ rec) {
    __shared__ int lc[NBK];               // 31.3KB
    int t = threadIdx.x;
    for (int i = t; i < NBK; i += 256) lc[i] = 0;
    __syncthreads();
    int e0 = blockIdx.x * CH;
    int e1 = e0 + CH; if (e1 > N_EDGES) e1 = N_EDGES;
    for (int e = e0 + t; e < e1; e += 256)
        atomicAdd(&lc[((edst[e] >> BSH) << 3) | (esrc[e] >> TSH)], 1);
    __syncthreads();
    for (int i = t; i < NBK; i += 256) {
        int c = lc[i];
        if (c) lc[i] = atomicAdd(&cursor[i], c);   // lc[i] becomes global base
    }
    __syncthreads();
    for (int e = e0 + t; e < e1; e += 256) {
        int dd = edst[e], ss = esrc[e];
        int key = ((dd >> BSH) << 3) | (ss >> TSH);
        int p = atomicAdd(&lc[key], 1);
        rec[p] = ((unsigned)(dd & (BSZ - 1)) << 19) | (unsigned)ss;
    }
}

// ---- K4: per-bucket LDS aggregation, register-batched gather --------------
// Identical structure to R5; records are now src-tile-ordered within the
// bucket, so co-resident blocks gather from ~one 4MB x-tile at a time ->
// XCD-local L2 hits instead of EA misses.
__global__ __launch_bounds__(512, 8) void reduce_k(
    const float* __restrict__ x, const unsigned* __restrict__ rec,
    const int* __restrict__ boffk, const float* __restrict__ Wl,
    const float* __restrict__ bl, const float* __restrict__ Wr,
    float* __restrict__ out) {
    __shared__ float slice[BSZ * D];     // 32KB fp32 accumulator
    __shared__ int scnt[BSZ];            // 2KB
    __shared__ unsigned srec[1024];      // 4KB staging
    int t = threadIdx.x;
    for (int i = t; i < BSZ * D; i += 512) slice[i] = 0.f;
    for (int i = t; i < BSZ; i += 512) scnt[i] = 0;

    int d = t & 15, g = t >> 4;          // 32 groups of 16 lanes
    int b = blockIdx.x;
    int beg = boffk[b << 3], end = boffk[(b + 1) << 3];

    for (int c0 = beg; c0 < end; c0 += 1024) {
        int cn = end - c0; if (cn > 1024) cn = 1024;
        __syncthreads();                  // also covers slice/scnt init
        for (int i = t; i < cn; i += 512) srec[i] = rec[c0 + i];
        __syncthreads();

        int nfull = cn >> 8;              // batches of 256 recs (8 per group)
        for (int bb = 0; bb < nfull; ++bb) {
            int base = bb * 256 + g * 8;
            unsigned rc[8];
#pragma unroll
            for (int j = 0; j < 8; ++j) rc[j] = srec[base + j];
            float v[8];
#pragma unroll
            for (int j = 0; j < 8; ++j)
                v[j] = x[(int)(rc[j] & 0x7FFFFu) * D + d];
#pragma unroll
            for (int j = 0; j < 8; ++j) {
                int nl = (int)(rc[j] >> 19);
                atomicAdd(&slice[nl * D + d], v[j]);
                if (d == 0) atomicAdd(&scnt[nl], 1);
            }
        }
        for (int i = (nfull << 8) + g; i < cn; i += 32) {
            unsigned rc = srec[i];
            atomicAdd(&slice[(int)(rc >> 19) * D + d], x[(int)(rc & 0x7FFFFu) * D + d]);
            if (d == 0) atomicAdd(&scnt[rc >> 19], 1);
        }
    }
    __syncthreads();

    // epilogue: mean + out = mean@Wl^T + bl + x@Wr^T
    float wl[D], wr[D];
    const float4* wl4 = (const float4*)(Wl + d * D);
    const float4* wr4 = (const float4*)(Wr + d * D);
#pragma unroll
    for (int q = 0; q < 4; ++q) {
        float4 a = wl4[q], b2 = wr4[q];
        wl[4*q]=a.x; wl[4*q+1]=a.y; wl[4*q+2]=a.z; wl[4*q+3]=a.w;
        wr[4*q]=b2.x; wr[4*q+1]=b2.y; wr[4*q+2]=b2.z; wr[4*q+3]=b2.w;
    }
    float bb2 = bl[d];
    int node0 = b << BSH;
    for (int n = g; n < BSZ; n += 32) {
        int node = node0 + n;
        if (node >= N_NODES) break;       // uniform within 16-lane group
        float m  = slice[n * D + d] / fmaxf((float)scnt[n], 1.f);
        float xv = x[node * D + d];
        float o  = bb2;
#pragma unroll
        for (int k = 0; k < D; ++k)
            o += __shfl(m, k, 16) * wl[k] + __shfl(xv, k, 16) * wr[k];
        out[node * D + d] = o;
    }
}

// ===================== fallback (R1 atomic path, needs only 2MB ws) ========
__global__ void sage_scatter(const float* __restrict__ x, const int* __restrict__ esrc,
                             const int* __restrict__ edst, float* __restrict__ agg,
                             float* __restrict__ cnt) {
    long long gid = (long long)blockIdx.x * blockDim.x + threadIdx.x;
    long long e = gid >> 4;
    int d = (int)(gid & 15);
    if (e >= N_EDGES) return;
    atomicAdd(&agg[(long long)edst[e] * D + d], x[(long long)esrc[e] * D + d]);
    if (d == 0) atomicAdd(&cnt[edst[e]], 1.0f);
}

__global__ void sage_finalize(const float* __restrict__ x, float* __restrict__ agg_out,
                              const float* __restrict__ cnt, const float* __restrict__ W_l,
                              const float* __restrict__ b_l, const float* __restrict__ W_r) {
    __shared__ float sWl[D * D], sWr[D * D], sb[D];
    int tid = threadIdx.x;
    if (tid < D * D) { sWl[tid] = W_l[tid]; sWr[tid] = W_r[tid]; }
    if (tid < D) sb[tid] = b_l[tid];
    __syncthreads();
    int i = blockIdx.x * blockDim.x + tid;
    if (i >= N_NODES) return;
    float inv = 1.0f / fmaxf(cnt[i], 1.0f);
    float m[D], xv[D];
    const float4* ap = (const float4*)(agg_out + (long long)i * D);
    const float4* xp = (const float4*)(x + (long long)i * D);
#pragma unroll
    for (int q = 0; q < 4; ++q) {
        float4 a = ap[q], b = xp[q];
        m[4*q]=a.x*inv; m[4*q+1]=a.y*inv; m[4*q+2]=a.z*inv; m[4*q+3]=a.w*inv;
        xv[4*q]=b.x; xv[4*q+1]=b.y; xv[4*q+2]=b.z; xv[4*q+3]=b.w;
    }
    float o[D];
#pragma unroll
    for (int oo = 0; oo < D; ++oo) {
        float a2 = sb[oo];
#pragma unroll
        for (int k = 0; k < D; ++k) a2 += m[k]*sWl[oo*D+k] + xv[k]*sWr[oo*D+k];
        o[oo] = a2;
    }
    float4* op = (float4*)(agg_out + (long long)i * D);
#pragma unroll
    for (int q = 0; q < 4; ++q)
        op[q] = make_float4(o[4*q], o[4*q+1], o[4*q+2], o[4*q+3]);
}

// ===================== launch =====================
extern "C" void kernel_launch(void* const* d_in, const int* in_sizes, int n_in,
                              void* d_out, int out_size, void* d_ws, size_t ws_size,
                              hipStream_t stream) {
    const float* x   = (const float*)d_in[0];
    const int*   ei  = (const int*)d_in[1];
    const float* W_l = (const float*)d_in[2];
    const float* b_l = (const float*)d_in[3];
    const float* W_r = (const float*)d_in[4];
    const int* esrc = ei;
    const int* edst = ei + N_EDGES;
    float* out = (float*)d_out;

    // ws layout: rec(5M u32) | bhist(NBK) | boffk(NBK+1) | cursor(NBK)
    size_t rec_b = (size_t)N_EDGES * 4;
    size_t need  = rec_b + (size_t)(3 * NBK + 1) * 4;

    if (ws_size >= need) {
        unsigned* rec = (unsigned*)d_ws;
        int* bhist  = (int*)((char*)d_ws + rec_b);
        int* boffk  = bhist + NBK;
        int* cursor = boffk + (NBK + 1);

        hipMemsetAsync(bhist, 0, (size_t)NBK * 4, stream);
        hist_k<<<512, 256, 0, stream>>>(esrc, edst, bhist);
        scan_k<<<1, 1024, 0, stream>>>(bhist, boffk, cursor);
        place_k<<<PBLK, 256, 0, stream>>>(esrc, edst, cursor, rec);
        reduce_k<<<NB, 512, 0, stream>>>(x, rec, boffk, W_l, b_l, W_r, out);
    } else {
        float* cntf = (float*)d_ws;
        hipMemsetAsync(out, 0, (size_t)N_NODES * D * sizeof(float), stream);
        hipMemsetAsync(cntf, 0, (size_t)N_NODES * sizeof(float), stream);
        long long total = (long long)N_EDGES * D;
        sage_scatter<<<(unsigned)((total + 255) / 256), 256, 0, stream>>>(x, esrc, edst, out, cntf);
        sage_finalize<<<(N_NODES + 255) / 256, 256, 0, stream>>>(x, out, cntf, W_l, b_l, W_r);
    }
}

// Round 7
// 583.636 us; speedup vs baseline: 1.0903x; 1.0903x over previous
//
#include <hip/hip_runtime.h>
#include <hip/hip_fp16.h>

#define N_NODES 500000
#define N_EDGES 5000000
#define D 16
#define BSH 9
#define BSZ 512                          // nodes per dst bucket
#define NB ((N_NODES + BSZ - 1) / BSZ)   // 977 dst buckets
#define CH 16384                         // edges per place-block chunk
#define PBLK ((N_EDGES + CH - 1) / CH)   // 306 blocks
#define NCK 4                            // dim chunks (4 dims each, fp16 -> 4MB table)
#define SLP 5                            // LDS slice stride (bank-spread padding)

// ---- K0: convert x to fp16, chunk-major: xh[c][node] = dims 4c..4c+3 ------
__global__ __launch_bounds__(256) void conv_k(const float* __restrict__ x,
                                              uint2* __restrict__ xh) {
    int i = blockIdx.x * blockDim.x + threadIdx.x;
    if (i >= N_NODES) return;
    const float4* xr = (const float4*)(x + (size_t)i * D);
#pragma unroll
    for (int c = 0; c < NCK; ++c) {
        float4 v = xr[c];
        __half2 a = __floats2half2_rn(v.x, v.y);
        __half2 b = __floats2half2_rn(v.z, v.w);
        uint2 u;
        u.x = *reinterpret_cast<unsigned*>(&a);
        u.y = *reinterpret_cast<unsigned*>(&b);
        xh[(size_t)c * N_NODES + i] = u;
    }
}

// ---- K1: dst-bucket histogram (LDS-privatized) ----------------------------
__global__ __launch_bounds__(256) void hist_k(const int* __restrict__ edst,
                                              int* __restrict__ bhist) {
    __shared__ int h[NB];
    for (int i = threadIdx.x; i < NB; i += 256) h[i] = 0;
    __syncthreads();
    int stride = gridDim.x * blockDim.x;
    for (int e = blockIdx.x * blockDim.x + threadIdx.x; e < N_EDGES; e += stride)
        atomicAdd(&h[edst[e] >> BSH], 1);
    __syncthreads();
    for (int i = threadIdx.x; i < NB; i += 256)
        if (h[i]) atomicAdd(&bhist[i], h[i]);
}

// ---- K2: exclusive scan of bucket totals (1 block) ------------------------
__global__ void scan_k(const int* __restrict__ bhist, int* __restrict__ boff,
                       int* __restrict__ cursor) {
    __shared__ int s[1024];
    int t = threadIdx.x;
    int v = (t < NB) ? bhist[t] : 0;
    s[t] = v; __syncthreads();
    for (int off = 1; off < 1024; off <<= 1) {
        int u = (t >= off) ? s[t - off] : 0;
        __syncthreads(); s[t] += u; __syncthreads();
    }
    if (t < NB) { int ex = s[t] - v; boff[t] = ex; cursor[t] = ex; }
    if (t == 0) boff[NB] = N_EDGES;
}

// ---- K3: bulk-reserve counting-sort placement -----------------------------
__global__ __launch_bounds__(256) void place_k(const int* __restrict__ esrc,
                                               const int* __restrict__ edst,
                                               int* __restrict__ cursor,
                                               unsigned* __restrict__ rec) {
    __shared__ int lc[NB];
    int t = threadIdx.x;
    for (int i = t; i < NB; i += 256) lc[i] = 0;
    __syncthreads();
    int e0 = blockIdx.x * CH;
    int e1 = e0 + CH; if (e1 > N_EDGES) e1 = N_EDGES;
    for (int e = e0 + t; e < e1; e += 256)
        atomicAdd(&lc[edst[e] >> BSH], 1);
    __syncthreads();
    for (int i = t; i < NB; i += 256) {
        int c = lc[i];
        if (c) lc[i] = atomicAdd(&cursor[i], c);
    }
    __syncthreads();
    for (int e = e0 + t; e < e1; e += 256) {
        int dd = edst[e];
        int p = atomicAdd(&lc[dd >> BSH], 1);
        rec[p] = ((unsigned)(dd & (BSZ - 1)) << 19) | (unsigned)esrc[e];
    }
}

// ---- K4: 4-pass L2-resident fp16 gather + LDS accumulate ------------------
// Pass c gathers 8B/edge from the 4MB chunk-c table (XCD-L2-resident).
// rec is read nontemporally so the stream doesn't evict the chunk.
__global__ __launch_bounds__(512, 8) void reduce_k(
    const uint2* __restrict__ xh, const unsigned* __restrict__ rec,
    const int* __restrict__ boff, float* __restrict__ sum,
    int* __restrict__ cnt) {
    __shared__ float slice[BSZ * SLP];   // 10.25KB
    __shared__ int scnt[BSZ];            // 2KB
    int t = threadIdx.x;
    int b = blockIdx.x;
    int beg = boff[b], end = boff[b + 1];
    int node0 = b << BSH;

#pragma unroll 1
    for (int c = 0; c < NCK; ++c) {
        for (int i = t; i < BSZ * SLP; i += 512) slice[i] = 0.f;
        if (c == 0) scnt[t] = 0;         // blockDim == BSZ
        __syncthreads();

        const uint2* tab = xh + (size_t)c * N_NODES;
        for (int i = beg + t; i < end; i += 512) {
            unsigned rc = __builtin_nontemporal_load(&rec[i]);
            int nl = (int)(rc >> 19);
            int s  = (int)(rc & 0x7FFFFu);
            uint2 u = tab[s];
            __half2 h0 = *reinterpret_cast<__half2*>(&u.x);
            __half2 h1 = *reinterpret_cast<__half2*>(&u.y);
            float2 f0 = __half22float2(h0);
            float2 f1 = __half22float2(h1);
            int base = nl * SLP;
            atomicAdd(&slice[base + 0], f0.x);
            atomicAdd(&slice[base + 1], f0.y);
            atomicAdd(&slice[base + 2], f1.x);
            atomicAdd(&slice[base + 3], f1.y);
            if (c == 0) atomicAdd(&scnt[nl], 1);
        }
        __syncthreads();

        int node = node0 + t;
        if (node < N_NODES) {
            float4 s4 = make_float4(slice[t * SLP], slice[t * SLP + 1],
                                    slice[t * SLP + 2], slice[t * SLP + 3]);
            ((float4*)sum)[(size_t)node * NCK + c] = s4;   // plain store: L2 merges quarters
            if (c == 0) cnt[node] = scnt[t];
        }
        __syncthreads();
    }
}

// ---- K5: mean + out = mean@Wl^T + bl + x@Wr^T (in-place on d_out) ---------
__global__ __launch_bounds__(256) void final_k(const float* __restrict__ x,
                                               float* __restrict__ sum_out,
                                               const int* __restrict__ cnt,
                                               const float* __restrict__ Wl,
                                               const float* __restrict__ bl,
                                               const float* __restrict__ Wr) {
    __shared__ float sWl[D * D], sWr[D * D], sb[D];
    int tid = threadIdx.x;
    if (tid < D * D) { sWl[tid] = Wl[tid]; sWr[tid] = Wr[tid]; }
    if (tid < D) sb[tid] = bl[tid];
    __syncthreads();
    int i = blockIdx.x * blockDim.x + tid;
    if (i >= N_NODES) return;
    float inv = 1.0f / fmaxf((float)cnt[i], 1.0f);
    float m[D], xv[D];
    const float4* ap = (const float4*)(sum_out + (size_t)i * D);
    const float4* xp = (const float4*)(x + (size_t)i * D);
#pragma unroll
    for (int q = 0; q < 4; ++q) {
        float4 a = ap[q], b = xp[q];
        m[4*q]=a.x*inv; m[4*q+1]=a.y*inv; m[4*q+2]=a.z*inv; m[4*q+3]=a.w*inv;
        xv[4*q]=b.x; xv[4*q+1]=b.y; xv[4*q+2]=b.z; xv[4*q+3]=b.w;
    }
    float o[D];
#pragma unroll
    for (int oo = 0; oo < D; ++oo) {
        float a2 = sb[oo];
#pragma unroll
        for (int k = 0; k < D; ++k) a2 += m[k]*sWl[oo*D+k] + xv[k]*sWr[oo*D+k];
        o[oo] = a2;
    }
    float4* op = (float4*)(sum_out + (size_t)i * D);
#pragma unroll
    for (int q = 0; q < 4; ++q)
        op[q] = make_float4(o[4*q], o[4*q+1], o[4*q+2], o[4*q+3]);
}

// ===================== fallback (R1 atomic path, needs only 2MB ws) ========
__global__ void sage_scatter(const float* __restrict__ x, const int* __restrict__ esrc,
                             const int* __restrict__ edst, float* __restrict__ agg,
                             float* __restrict__ cnt) {
    long long gid = (long long)blockIdx.x * blockDim.x + threadIdx.x;
    long long e = gid >> 4;
    int d = (int)(gid & 15);
    if (e >= N_EDGES) return;
    atomicAdd(&agg[(long long)edst[e] * D + d], x[(long long)esrc[e] * D + d]);
    if (d == 0) atomicAdd(&cnt[edst[e]], 1.0f);
}

__global__ void sage_finalize(const float* __restrict__ x, float* __restrict__ agg_out,
                              const float* __restrict__ cnt, const float* __restrict__ W_l,
                              const float* __restrict__ b_l, const float* __restrict__ W_r) {
    __shared__ float sWl[D * D], sWr[D * D], sb[D];
    int tid = threadIdx.x;
    if (tid < D * D) { sWl[tid] = W_l[tid]; sWr[tid] = W_r[tid]; }
    if (tid < D) sb[tid] = b_l[tid];
    __syncthreads();
    int i = blockIdx.x * blockDim.x + tid;
    if (i >= N_NODES) return;
    float inv = 1.0f / fmaxf(cnt[i], 1.0f);
    float m[D], xv[D];
    const float4* ap = (const float4*)(agg_out + (long long)i * D);
    const float4* xp = (const float4*)(x + (long long)i * D);
#pragma unroll
    for (int q = 0; q < 4; ++q) {
        float4 a = ap[q], b = xp[q];
        m[4*q]=a.x*inv; m[4*q+1]=a.y*inv; m[4*q+2]=a.z*inv; m[4*q+3]=a.w*inv;
        xv[4*q]=b.x; xv[4*q+1]=b.y; xv[4*q+2]=b.z; xv[4*q+3]=b.w;
    }
    float o[D];
#pragma unroll
    for (int oo = 0; oo < D; ++oo) {
        float a2 = sb[oo];
#pragma unroll
        for (int k = 0; k < D; ++k) a2 += m[k]*sWl[oo*D+k] + xv[k]*sWr[oo*D+k];
        o[oo] = a2;
    }
    float4* op = (float4*)(agg_out + (long long)i * D);
#pragma unroll
    for (int q = 0; q < 4; ++q)
        op[q] = make_float4(o[4*q], o[4*q+1], o[4*q+2], o[4*q+3]);
}

// ===================== launch =====================
extern "C" void kernel_launch(void* const* d_in, const int* in_sizes, int n_in,
                              void* d_out, int out_size, void* d_ws, size_t ws_size,
                              hipStream_t stream) {
    const float* x   = (const float*)d_in[0];
    const int*   ei  = (const int*)d_in[1];
    const float* W_l = (const float*)d_in[2];
    const float* b_l = (const float*)d_in[3];
    const float* W_r = (const float*)d_in[4];
    const int* esrc = ei;
    const int* edst = ei + N_EDGES;
    float* out = (float*)d_out;

    // ws layout: xh (16MB) | rec (20MB) | cnt (2MB) | bhist | boff | cursor
    size_t xh_b   = (size_t)NCK * N_NODES * 8;       // uint2 per node per chunk
    size_t rec_b  = (size_t)N_EDGES * 4;
    size_t cnt_b  = (size_t)N_NODES * 4;
    size_t need   = xh_b + rec_b + cnt_b + (size_t)(3 * NB + 1) * 4;

    if (ws_size >= need) {
        uint2*    xh     = (uint2*)d_ws;
        unsigned* rec    = (unsigned*)((char*)d_ws + xh_b);
        int*      cnt    = (int*)((char*)d_ws + xh_b + rec_b);
        int*      bhist  = cnt + N_NODES;
        int*      boff   = bhist + NB;
        int*      cursor = boff + (NB + 1);

        hipMemsetAsync(bhist, 0, (size_t)NB * 4, stream);
        conv_k<<<(N_NODES + 255) / 256, 256, 0, stream>>>(x, xh);
        hist_k<<<512, 256, 0, stream>>>(edst, bhist);
        scan_k<<<1, 1024, 0, stream>>>(bhist, boff, cursor);
        place_k<<<PBLK, 256, 0, stream>>>(esrc, edst, cursor, rec);
        reduce_k<<<NB, 512, 0, stream>>>(xh, rec, boff, out, cnt);
        final_k<<<(N_NODES + 255) / 256, 256, 0, stream>>>(x, out, cnt, W_l, b_l, W_r);
    } else {
        float* cntf = (float*)d_ws;
        hipMemsetAsync(out, 0, (size_t)N_NODES * D * sizeof(float), stream);
        hipMemsetAsync(cntf, 0, (size_t)N_NODES * sizeof(float), stream);
        long long total = (long long)N_EDGES * D;
        sage_scatter<<<(unsigned)((total + 255) / 256), 256, 0, stream>>>(x, esrc, edst, out, cntf);
        sage_finalize<<<(N_NODES + 255) / 256, 256, 0, stream>>>(x, out, cntf, W_l, b_l, W_r);
    }
}